// Round 9
// baseline (2767.571 us; speedup 1.0000x reference)
//
#include <hip/hip_runtime.h>
#include <math.h>

// ---------------------------------------------------------------------------
// HFPS R20: fuse panelR into trail (-16 barriers), agent-scope barrier.
// R19 post-mortem: RMW-free barrier changed nothing (1237->1230) => barrier
// cost is NOT signaling; it's the release/acquire L2-writeback+invalidate
// (per-XCD L2 non-coherent, coherence at LLC) -> every phase restarts cold.
// Scales with barrier COUNT. This round:
//   - panelR deleted. The transformed panel is consumed ONLY by trail's
//     staging (A subdiagonal is dead otherwise), so each trail block applies
//     the 32-step panel recurrence to the rows it stages (bit-identical shfl
//     code), writing directly into widened LDS staging (both lh halves,
//     67 KB) with invL folded into the j-side write. 26 barriers (was 42).
//   - barrier release-stores AGENT scope (LLC is the device coherence
//     point); polls stay SYSTEM; acquire agent fences unchanged.
// Conv/buildAvv/buildAs/factor_lds byte-identical to R18/R19.
//
// Workspace layout:
//   0 lacc, 8 nneg, 1024 logJ, 1088 nidx[1024]
//   5248 go (4B), 6144 slots[256] (8B apart)
//   8192 hist0, 41216 hist1
//   74240 tbuf/ybuf/hbuf0/hbuf1 (4 x 64*2304 fp32), 2433536 A (1048^2 f64)
// ---------------------------------------------------------------------------

#define NPIX 2304
#define MSZ  4608
#define NOCC 1024
#define NHID 24
#define PF_N 1048

__device__ __forceinline__ void gbar(unsigned* slots, unsigned* go,
                                     unsigned ep){
  __syncthreads();
  const int bid = blockIdx.x, tid = threadIdx.x;
  if (bid == 0){
    if (tid == 0)
      __hip_atomic_store(slots, ep, __ATOMIC_RELEASE,
                         __HIP_MEMORY_SCOPE_AGENT);
    for (;;){
      unsigned v = __hip_atomic_load(slots + tid*2, __ATOMIC_RELAXED,
                                     __HIP_MEMORY_SCOPE_SYSTEM);
      if (__syncthreads_count((v >= ep) ? 1 : 0) == 256) break;
      __builtin_amdgcn_s_sleep(1);
    }
    if (tid == 0){
      __builtin_amdgcn_fence(__ATOMIC_ACQUIRE, "agent");
      __hip_atomic_store(go, ep, __ATOMIC_RELEASE,
                         __HIP_MEMORY_SCOPE_AGENT);
    }
    __syncthreads();
  } else {
    if (tid == 0){
      __hip_atomic_store(slots + bid*2, ep, __ATOMIC_RELEASE,
                         __HIP_MEMORY_SCOPE_AGENT);
      int spins = 0;
      while (__hip_atomic_load(go, __ATOMIC_RELAXED,
                               __HIP_MEMORY_SCOPE_SYSTEM) < ep){
        __builtin_amdgcn_s_sleep(1);
        if (++spins >= 8192){        // watchdog: refresh arrival store
          spins = 0;
          __hip_atomic_store(slots + bid*2, ep, __ATOMIC_RELEASE,
                             __HIP_MEMORY_SCOPE_AGENT);
        }
      }
      __builtin_amdgcn_fence(__ATOMIC_ACQUIRE, "agent");
    }
    __syncthreads();
  }
}

__device__ __forceinline__ float gelu_f(float v){
  float v3 = v*v*v;
  return 0.5f*v*(1.0f + tanhf(0.7978845608028654f*(v + 0.044715f*v3)));
}

__device__ __forceinline__ void ld15(float* d, const float* b_,
                                     int ym, int y0, int yp, const int* c5){
  #pragma unroll
  for (int rr = 0; rr < 3; rr++){
    const int rb = (rr == 0) ? ym : ((rr == 1) ? y0 : yp);
    #pragma unroll
    for (int t = 0; t < 5; t++) d[rr*5+t] = b_[rb + c5[t]];
  }
}

// ---- one conv unit: channel c, rowgroup rg; 128 threads (ltid 0..127) ----
__device__ __forceinline__ void conv_unit(int u, int tid,
    const float* __restrict__ in, const float* __restrict__ wgt,
    const float* __restrict__ bias, const float* __restrict__ res,
    float* __restrict__ outp, float* __restrict__ pre_out,
    double* __restrict__ logJ_acc,
    int cin, int resmode, int dogelu, float scale, float pre_scale){
  const int c  = u / 6;
  const int rg = u % 6;
  const int y  = rg*8 + (tid >> 4);
  const int xg = (tid & 15)*3;
  const int ym = ((y+47)%48)*48, y0 = y*48, yp = ((y+1)%48)*48;
  int c5[5];
  #pragma unroll
  for (int t = 0; t < 5; t++){
    int xx = xg - 1 + t;
    c5[t] = (xx < 0) ? 47 : ((xx >= 48) ? xx - 48 : xx);
  }
  float s0 = 0.f, s1 = 0.f, s2 = 0.f;
  const float* wp = wgt + c*cin*9;
  float cv[15], nv[15];
  ld15(cv, in, ym, y0, yp, c5);
  for (int ci = 0; ci < cin; ci++){
    const bool more = (ci + 1 < cin);
    if (more) ld15(nv, in + (ci+1)*NPIX, ym, y0, yp, c5);
    #pragma unroll
    for (int rr = 0; rr < 3; rr++){
      float v0 = cv[rr*5+0], v1 = cv[rr*5+1], v2 = cv[rr*5+2];
      float v3 = cv[rr*5+3], v4 = cv[rr*5+4];
      float w0 = wp[3*rr], w1 = wp[3*rr+1], w2 = wp[3*rr+2];
      s0 += v0*w0 + v1*w1 + v2*w2;
      s1 += v1*w0 + v2*w1 + v3*w2;
      s2 += v2*w0 + v3*w1 + v4*w2;
    }
    if (more){
      #pragma unroll
      for (int q2 = 0; q2 < 15; q2++) cv[q2] = nv[q2];
    }
    wp += 9;
  }
  const float bv = bias ? bias[c] : 0.f;
  const int base = c*NPIX + y0 + xg;
  float sv[3] = {s0, s1, s2};
  double ls = 0.0;
  #pragma unroll
  for (int t = 0; t < 3; t++){
    float s = sv[t] + bv;
    if (dogelu) s = gelu_f(s);
    if (resmode == 1) s += res[c*NPIX + y0 + xg + t];
    else if (resmode == 2) s += res[(c>>5)*NPIX + y0 + xg + t];
    s *= scale;
    outp[base+t] = s;
    if (pre_out) pre_out[base+t] = gelu_f(s * pre_scale);
    ls += (double)s;
  }
  if (logJ_acc && c >= 48){
    for (int o = 32; o > 0; o >>= 1) ls += __shfl_down(ls, o, 64);
    if ((tid & 63) == 0) atomicAdd(logJ_acc, ls);
  }
}

// ---- one 32x32 buildAvv tile (whole 256-thread block) ----
__device__ void build_avv_tile(int item, const float* __restrict__ Fvv,
      const int* __restrict__ nidx, double* __restrict__ A,
      float* G1, float* G2, int* sNi, int* sNj){
  __syncthreads();                       // protect LDS reuse across tiles
  int I = 0;
  while ((I+1)*(I+2)/2 <= item) I++;
  const int J = item - I*(I+1)/2;
  const int i0 = I*32, j0 = J*32;
  const int tid = threadIdx.x;
  if (tid < 32) sNi[tid] = nidx[i0+tid];
  else if (tid < 64) sNj[tid-32] = nidx[j0+tid-32];
  __syncthreads();
  for (int idx = tid; idx < 32*32; idx += 256){
    const int r = idx >> 5, c = idx & 31;
    G1[r*33+c] = Fvv[(size_t)sNi[r]*MSZ + sNj[c]];
    G2[r*33+c] = Fvv[(size_t)sNj[r]*MSZ + sNi[c]];
  }
  __syncthreads();
  for (int idx = tid; idx < 32*32; idx += 256){
    const int r = idx >> 5, c = idx & 31;
    const int i = i0 + r, j = j0 + c;
    if (i > j)
      A[(size_t)i*PF_N + j] = 0.5*((double)G1[r*33+c] - (double)G2[c*33+r]);
  }
}

// ---- 2x2-pivot factorization of a diag tile in LDS (proven R11-R19) ----
__device__ __forceinline__ void factor_lds(double* D, double* sTf, int w,
      double* __restrict__ histN, double& lv_out, int& sg_out){
  const int tid = threadIdx.x;
  const int r = tid & 63, qu = tid >> 6;
  const int np = w >> 1;
  for (int j = 0; j < np; j++){
    const int r0 = 2*j, r1 = r0 + 1;
    const double t = -D[r1*65 + r0];
    const double invt = 1.0 / t;
    if (tid == 0) sTf[j] = t;
    const bool rowok = (r < w) && (r >= r0 + 2);
    if (rowok){
      const double ar = D[r*65 + r0], br = D[r*65 + r1];
      if (qu == 0){
        histN[32 + j*64 + r]        = ar * invt;
        histN[32 + 2048 + j*64 + r] = br * invt;
      }
      const int lo = r0 + 2, hi = r;
      const int per = (hi - lo + 3) >> 2;
      const int cb = lo + qu*per;
      int ce = cb + per; if (ce > hi) ce = hi;
      for (int c = cb; c < ce; c++){
        const double ac = D[c*65 + r0], bc = D[c*65 + r1];
        D[r*65 + c] += (br*ac - ar*bc) * invt;
      }
    }
    __syncthreads();
  }
  if (tid < np) histN[tid] = 1.0 / sTf[tid];
  lv_out = 0.0; sg_out = 0;
  if (tid < 64){
    double lv = 0.0; int sg = 0;
    if (tid < np){ double t = sTf[tid]; lv = log(fabs(t)); sg = (t < 0.0) ? 1 : 0; }
    for (int o = 32; o > 0; o >>= 1){
      lv += __shfl_down(lv, o, 64);
      sg += __shfl_down(sg, o, 64);
    }
    if (tid == 0){ lv_out = lv; sg_out = sg; }
  }
}

// ---------------------------------------------------------------------------
__global__ __launch_bounds__(256) void k_mega(
    const float* __restrict__ x, const float* __restrict__ Fvv,
    const float* __restrict__ Fhh,
    const float* __restrict__ w10, const float* __restrict__ b10,
    const float* __restrict__ w20, const float* __restrict__ b20,
    const float* __restrict__ w11, const float* __restrict__ b11,
    const float* __restrict__ w21, const float* __restrict__ b21,
    const float* __restrict__ w12, const float* __restrict__ b12,
    const float* __restrict__ w22, const float* __restrict__ b22,
    const float* __restrict__ w13, const float* __restrict__ b13,
    const float* __restrict__ w23,
    float* __restrict__ outp,
    double* __restrict__ lacc, int* __restrict__ nneg,
    double* __restrict__ logJa, int* __restrict__ nidx,
    double* __restrict__ hist0, double* __restrict__ hist1,
    float* __restrict__ tbuf, float* __restrict__ ybuf,
    float* __restrict__ hbuf0, float* __restrict__ hbuf1,
    double* __restrict__ A, unsigned* __restrict__ slots,
    unsigned* __restrict__ go){
  const int bid = blockIdx.x, tid = threadIdx.x;
  unsigned ep = 0;                 // barrier epoch
  __shared__ double shU[8448];     // union: prep / G1G2 / D / dual-lh staging
  __shared__ double sInvL[32];
  __shared__ double sTf[32];

  // ---- P0: prep (block 0): nidx, tbuf = x/sqrt(2), zero accumulators ----
  if (bid == 0){
    int* cnt = (int*)shU; int* off = cnt + 256;
    if (tid == 0){ *lacc = 0.0; *nneg = 0; *logJa = 0.0; }
    int c = 0;
    for (int k2 = 0; k2 < 18; k2++){
      int idx = tid*18 + k2;
      float v = x[idx];
      c += (v == 1.0f) ? 1 : 0;
      tbuf[idx] = v * 0.70710678118654752f;
    }
    cnt[tid] = c;
    __syncthreads();
    if (tid == 0){ int s = 0; for (int q=0;q<256;q++){ off[q]=s; s+=cnt[q]; } }
    __syncthreads();
    int o = off[tid];
    for (int k2 = 0; k2 < 18; k2++){
      int idx = tid*18+k2;
      if (x[idx] == 1.0f) nidx[o++] = idx;
    }
  }
  gbar(slots, go, ++ep);

  // ---- P1..P8: conv layers (bids 0..191) || buildAvv (192..254)
  //      || factor of diag tile 0 on bid 255 during P2 ----
  const float* cin_p[8] = {tbuf,ybuf,tbuf,ybuf,tbuf,ybuf,tbuf,ybuf};
  const float* w_p[8]   = {w10,w20,w11,w21,w12,w22,w13,w23};
  const float* b_p[8]   = {b10,b20,b11,b21,b12,b22,b13,nullptr};
  const float* r_p[8]   = {nullptr,x,nullptr,hbuf0,nullptr,hbuf1,nullptr,hbuf0};
  float* o_p[8]         = {ybuf,hbuf0,ybuf,hbuf1,ybuf,hbuf0,ybuf,hbuf1};
  float* pre_p[8]       = {nullptr,tbuf,nullptr,tbuf,nullptr,tbuf,nullptr,nullptr};
  const int   cinn[8]   = {2,64,64,64,64,64,64,64};
  const int   rm[8]     = {0,2,0,1,0,1,0,1};
  const int   dg[8]     = {1,0,1,0,1,0,1,0};
  const float sc[8]     = {1.f,1.f,1.f,1.f,1.f,1.f,1.f,0.44721359549995794f};
  const float ps[8]     = {0.f,0.70710678118654752f,0.f,0.57735026918962576f,
                           0.f,0.5f,0.f,0.f};
  #pragma unroll
  for (int p = 1; p <= 8; p++){
    if (bid < 192){
      conv_unit(bid*2 + (tid>>7), tid & 127,
                cin_p[p-1], w_p[p-1], b_p[p-1], r_p[p-1], o_p[p-1], pre_p[p-1],
                (p == 8) ? logJa : nullptr,
                cinn[p-1], rm[p-1], dg[p-1], sc[p-1], ps[p-1]);
    } else if (bid < 255){
      float* G1 = (float*)shU;
      float* G2 = G1 + 32*33;
      int* sNi = (int*)(G2 + 32*33);
      int* sNj = sNi + 32;
      for (int t = (p-1)*66 + (bid-192); t < p*66; t += 63)
        build_avv_tile(t, Fvv, nidx, A, G1, G2, sNi, sNj);
    } else if (p == 2){
      // diag tile 0 factor (A-tile built in P1), hidden under conv L2
      for (int idx = tid; idx < 64*64; idx += 256){
        int r = idx >> 6, c = idx & 63;
        if (r > c) shU[r*65+c] = A[(size_t)r*PF_N + c];
      }
      __syncthreads();
      double lv; int sg;
      factor_lds(shU, sTf, 64, hist0, lv, sg);
      if (tid == 0){ atomicAdd(lacc, lv); atomicAdd(nneg, sg); }
    }
    gbar(slots, go, ++ep);
  }

  // ---- P9: buildAs strip (rows 1024..1047) ----
  {
    int g0 = bid*256 + tid;
    if (g0 < 24*PF_N){
      const int i = NOCC + g0 / PF_N, j = g0 % PF_N;
      if (j < i){
        const int r = i - NOCC;
        double v;
        if (j < NOCC){
          int nj = nidx[j];
          int ss = (nj >= NPIX) ? 1 : 0;
          v = -(double)hbuf1[(2*r+ss)*NPIX + (nj - ss*NPIX)];
        } else {
          int r2 = j - NOCC;
          v = 0.5*((double)Fhh[r*NHID + r2] - (double)Fhh[r2*NHID + r]);
        }
        A[(size_t)i*PF_N + j] = v;
      }
    }
  }
  gbar(slots, go, ++ep);

  // ---- Pfaffian loop: 16 x (fused panel-transform + trail + factor; bar) --
  for (int k = 0; k < 16; k++){
    const double* hR = (k & 1) ? hist1 : hist0;
    double* hW = (k & 1) ? hist0 : hist1;
    const int N = PF_N, c0 = 64*k, tc0 = c0 + 64;
    const int m = N - tc0;
    const int nt = (m + 63) >> 6;
    const int items = nt*(nt+1)/2;
    const int ty = tid >> 4, tx = tid & 15;
    const int wv = tid >> 6, lc = tid & 63;
    int i0 = tc0, j0 = tc0, iend = tc0, jend = tc0;
    double acc[4][4];
    if (bid < items){
      {
        int I = 0, item = bid;
        while ((I+1)*(I+2)/2 <= item) I++;
        const int J = item - I*(I+1)/2;
        i0 = tc0 + I*64; j0 = tc0 + J*64;
      }
      iend = (i0 + 64 < N) ? (i0 + 64) : N;
      jend = (j0 + 64 < N) ? (j0 + 64) : N;
      if (tid < 32) sInvL[tid] = hR[tid];
      #pragma unroll
      for (int rr = 0; rr < 4; rr++)
        #pragma unroll
        for (int cc = 0; cc < 4; cc++){
          const int i = i0 + ty + 16*rr, j = j0 + tx + 16*cc;
          acc[rr][cc] = (i < iend && j < jend && i > j) ? A[(size_t)i*N + j] : 0.0;
        }
      __syncthreads();            // sInvL ready; shU free (post-gbar)
      const double* hA = hR + 32;
      const double* hB = hR + 32 + 2048;
      const bool diag = (i0 == j0);
      // in-block panel transform (bit-identical to old panelR recurrence),
      // written transposed into dual-lh staging; invL folded into j-side.
      #pragma unroll 1
      for (int rr = 0; rr < 16; rr++){
        const int r = wv*16 + rr;
        const int gi = i0 + r;
        double v = (gi < iend) ? A[(size_t)gi*N + c0 + lc] : 0.0;
        #pragma unroll 8
        for (int j = 0; j < 32; j++){
          double a = __shfl(v, 2*j,   64);
          double b = __shfl(v, 2*j+1, 64);
          if (lc >= 2*j+2) v += b*hA[j*64+lc] - a*hB[j*64+lc];
        }
        const int l = lc >> 1, lh = l >> 4, ll = l & 15;
        double* base = shU + lh*4224 + ((lc & 1) ? 1056 : 0);
        base[ll*66 + r] = v;
        if (diag) base[2112 + ll*66 + r] = v * sInvL[l];
      }
      if (!diag){
        #pragma unroll 1
        for (int rr = 0; rr < 16; rr++){
          const int r = wv*16 + rr;
          const int gj = j0 + r;
          double v = (gj < jend) ? A[(size_t)gj*N + c0 + lc] : 0.0;
          #pragma unroll 8
          for (int j = 0; j < 32; j++){
            double a = __shfl(v, 2*j,   64);
            double b = __shfl(v, 2*j+1, 64);
            if (lc >= 2*j+2) v += b*hA[j*64+lc] - a*hB[j*64+lc];
          }
          const int l = lc >> 1, lh = l >> 4, ll = l & 15;
          double* base = shU + lh*4224 + 2112 + ((lc & 1) ? 1056 : 0);
          base[ll*66 + r] = v * sInvL[l];
        }
      }
      __syncthreads();
      // MAC: l = 0..31 ascending == old lh0(ll0..15), lh1(ll0..15) order
      #pragma unroll 4
      for (int l = 0; l < 32; l++){
        const int lh = l >> 4, ll = l & 15;
        const double* sPiA = shU + lh*4224;
        const double* sPiB = sPiA + 1056;
        const double* sPjA = sPiA + 2112;
        const double* sPjB = sPiA + 3168;
        double ar[4], br[4], ac2[4], bc2[4];
        #pragma unroll
        for (int rr = 0; rr < 4; rr++){
          ar[rr] = sPiA[ll*66 + ty + 16*rr];
          br[rr] = sPiB[ll*66 + ty + 16*rr];
        }
        #pragma unroll
        for (int cc = 0; cc < 4; cc++){
          ac2[cc] = sPjA[ll*66 + tx + 16*cc];
          bc2[cc] = sPjB[ll*66 + tx + 16*cc];
        }
        #pragma unroll
        for (int rr = 0; rr < 4; rr++)
          #pragma unroll
          for (int cc = 0; cc < 4; cc++)
            acc[rr][cc] += br[rr]*ac2[cc] - ar[rr]*bc2[cc];
      }
      #pragma unroll
      for (int rr = 0; rr < 4; rr++)
        #pragma unroll
        for (int cc = 0; cc < 4; cc++){
          const int i = i0 + ty + 16*rr, j = j0 + tx + 16*cc;
          if (i < iend && j < jend && i > j) A[(size_t)i*N + j] = acc[rr][cc];
        }
    }
    if (bid == 0){
      __syncthreads();
      const int wn = iend - i0;           // 64 or tail 24
      #pragma unroll
      for (int rr = 0; rr < 4; rr++)
        #pragma unroll
        for (int cc = 0; cc < 4; cc++){
          const int i = i0 + ty + 16*rr, j = j0 + tx + 16*cc;
          if (i < iend && j < jend && i > j)
            shU[(i - i0)*65 + (j - j0)] = acc[rr][cc];
        }
      __syncthreads();
      double lv; int sg;
      factor_lds(shU, sTf, wn, hW, lv, sg);
      if (tid == 0){
        double lold = atomicAdd(lacc, lv);
        int sold = atomicAdd(nneg, sg);
        if (k == 15){
          int stot = sold + sg;
          outp[0] = (stot & 1) ? -1.0f : 1.0f;
          outp[1] = (float)(lold + lv + logJa[0]);
        }
      }
    }
    gbar(slots, go, ++ep);
  }
}

// ---------------------------------------------------------------------------
extern "C" void kernel_launch(void* const* d_in, const int* in_sizes, int n_in,
                              void* d_out, int out_size, void* d_ws, size_t ws_size,
                              hipStream_t stream){
  (void)in_sizes; (void)n_in; (void)out_size; (void)ws_size;
  const float* x   = (const float*)d_in[0];
  const float* Fvv = (const float*)d_in[1];
  const float* Fhh = (const float*)d_in[2];
  const float* w10 = (const float*)d_in[3];
  const float* b10 = (const float*)d_in[4];
  const float* w20 = (const float*)d_in[5];
  const float* b20 = (const float*)d_in[6];
  const float* w11 = (const float*)d_in[7];
  const float* b11 = (const float*)d_in[8];
  const float* w21 = (const float*)d_in[9];
  const float* b21 = (const float*)d_in[10];
  const float* w12 = (const float*)d_in[11];
  const float* b12 = (const float*)d_in[12];
  const float* w22 = (const float*)d_in[13];
  const float* b22 = (const float*)d_in[14];
  const float* w13 = (const float*)d_in[15];
  const float* b13 = (const float*)d_in[16];
  const float* w23 = (const float*)d_in[17];
  float* outp = (float*)d_out;

  char* ws = (char*)d_ws;
  double* lacc  = (double*)(ws + 0);
  int*    nneg  = (int*)(ws + 8);
  double* logJa = (double*)(ws + 1024);
  int*    nidx  = (int*)(ws + 1088);
  unsigned* go    = (unsigned*)(ws + 5248);
  unsigned* slots = (unsigned*)(ws + 6144);   // 256 slots, 8B apart
  double* hist0 = (double*)(ws + 8192);
  double* hist1 = (double*)(ws + 41216);
  const size_t CB = 589824;  // 64*2304*4
  float* tbuf  = (float*)(ws + 74240);
  float* ybuf  = (float*)(ws + 74240 + CB);
  float* hbuf0 = (float*)(ws + 74240 + 2*CB);
  float* hbuf1 = (float*)(ws + 74240 + 3*CB);
  double* A    = (double*)(ws + 74240 + 4*CB);

  hipMemsetAsync(ws + 5184, 0, 3008, stream);   // go + slots

  void* args[] = { &x,&Fvv,&Fhh,&w10,&b10,&w20,&b20,&w11,&b11,&w21,&b21,
                   &w12,&b12,&w22,&b22,&w13,&b13,&w23,&outp,
                   &lacc,&nneg,&logJa,&nidx,&hist0,&hist1,
                   &tbuf,&ybuf,&hbuf0,&hbuf1,&A,&slots,&go };
  hipLaunchCooperativeKernel((void*)k_mega, dim3(256), dim3(256), args, 0, stream);
}